// Round 1
// baseline (1465.682 us; speedup 1.0000x reference)
//
#include <hip/hip_runtime.h>
#include <cstdint>
#include <cstddef>

typedef unsigned short u16;
typedef unsigned int   u32;
typedef __attribute__((ext_vector_type(8))) short bf16x8;
typedef __attribute__((ext_vector_type(4))) float f32x4;

#define NB   16
#define LL   1024
#define CIN  300
#define XPB  (LL*CIN)      /* 307200 elements per batch */
#define XEL  (NB*XPB)      /* 4915200 */
#define NCH  6000
#define NCHP 6016          /* padded to 47*128 */
#define ODIM 100

#define BM 64
#define BN 128
#define BK 64
#define STR 72             /* LDS row stride (elements): 36 dwords -> max 2-way bank aliasing (free) */

__device__ __forceinline__ u16 f2bf(float f) {
  union { float f; u32 u; } v; v.f = f;
  return (u16)((v.u + 0x7FFFu + ((v.u >> 16) & 1u)) >> 16);   // RNE, inputs are finite
}

__device__ __forceinline__ void gparams(int g, int& K, int& Kp, int& woff) {
  if (g == 0)      { K = 600;  Kp = 640;  woff = 0; }
  else if (g == 1) { K = 900;  Kp = 960;  woff = NCHP*640; }
  else             { K = 1200; Kp = 1216; woff = NCHP*640 + NCHP*960; }
}

// ---- x (f32) -> xb (bf16), flat copy -------------------------------------
__global__ void cvt_x_kernel(const float* __restrict__ x, u16* __restrict__ xb) {
  int i = (blockIdx.x * 256 + threadIdx.x) * 8;   // grid sized exactly: XEL/(256*8)=2400
  float4 a = *(const float4*)(x + i);
  float4 b = *(const float4*)(x + i + 4);
  uint4 o;
  o.x = (u32)f2bf(a.x) | ((u32)f2bf(a.y) << 16);
  o.y = (u32)f2bf(a.z) | ((u32)f2bf(a.w) << 16);
  o.z = (u32)f2bf(b.x) | ((u32)f2bf(b.y) << 16);
  o.w = (u32)f2bf(b.z) | ((u32)f2bf(b.w) << 16);
  *(uint4*)(xb + i) = o;
}

// ---- W[n,o,c,j] (f32) -> Wb[no][kp=j*300+c] (bf16, K zero-padded to Kp, rows padded to 6016)
__global__ void repack_w_kernel(const float* __restrict__ W2, const float* __restrict__ W3,
                                const float* __restrict__ W4, u16* __restrict__ wb) {
  int g = blockIdx.y;
  int K, Kp, woff; gparams(g, K, Kp, woff);
  int kk = g + 2;
  const float* W = (g == 0) ? W2 : (g == 1) ? W3 : W4;
  int no = blockIdx.x;                       // 0..6015
  u16* dst = wb + (size_t)woff + (size_t)no * Kp;
  const float* src = W + (size_t)no * K;     // row no: [c][j], 300*k elements
  for (int kp = threadIdx.x; kp < Kp; kp += 256) {
    u16 v = 0;
    if (no < NCH && kp < K) {
      int j = kp / CIN, c = kp - j * CIN;
      v = f2bf(src[c * kk + j]);
    }
    dst[kp] = v;
  }
}

// ---- fused GEMM + running-max + bias + relu ------------------------------
__global__ __launch_bounds__(256, 2)
void gemm_max_kernel(const u16* __restrict__ xb, const u16* __restrict__ wb,
                     const float* __restrict__ b2v, const float* __restrict__ b3v,
                     const float* __restrict__ b4v, float* __restrict__ out) {
  const int chblk = blockIdx.x;    // 0..46
  const int b     = blockIdx.y;    // 0..15
  const int g     = blockIdx.z;    // 0..2  (kernel size g+2)
  int K, Kp, woff; gparams(g, K, Kp, woff);
  const int Lt = LL - (g + 2) + 1; // valid output positions

  __shared__ __align__(16) u16 As[BM * STR];
  __shared__ __align__(16) u16 Bs[BN * STR];

  const int tid  = threadIdx.x;
  const int lane = tid & 63;
  const int w    = tid >> 6;       // wave id 0..3 -> owns channels w*32..w*32+31

  const u16* __restrict__ xrow = xb + (size_t)b * XPB;
  const u16* __restrict__ Wg   = wb + (size_t)woff + (size_t)chblk * BN * Kp;

  float rmax[2] = { -1e30f, -1e30f };

  const int nkstep = Kp / BK;      // 10 / 15 / 19

  for (int t0 = 0; t0 < LL; t0 += BM) {
    f32x4 acc[4][2];
    #pragma unroll
    for (int mi = 0; mi < 4; mi++)
      #pragma unroll
      for (int ni = 0; ni < 2; ni++)
        acc[mi][ni] = (f32x4){0.f, 0.f, 0.f, 0.f};

    for (int ks = 0; ks < nkstep; ks++) {
      const int kk = ks * BK;
      // stage A tile [64 rows][64 kp], 2 chunks of 8 bf16 per thread, 4-elem zero-fill masks
      #pragma unroll
      for (int i = 0; i < 2; i++) {
        int c = tid + i * 256;                 // 0..511
        int row = c >> 3, col8 = (c & 7) * 8;
        int kp = kk + col8;
        int e  = (t0 + row) * CIN + kp;        // within-batch flat element
        const u16* src = xrow + e;
        uint2 lo = make_uint2(0u, 0u), hi = make_uint2(0u, 0u);
        if (kp + 4 <= K && e + 4 <= XPB) lo = *(const uint2*)(src);
        if (kp + 8 <= K && e + 8 <= XPB) hi = *(const uint2*)(src + 4);
        *(uint4*)(&As[row * STR + col8]) = make_uint4(lo.x, lo.y, hi.x, hi.y);
      }
      // stage B tile [128 ch][64 kp], 4 chunks per thread, pre-padded (no masks)
      #pragma unroll
      for (int i = 0; i < 4; i++) {
        int c = tid + i * 256;                 // 0..1023
        int row = c >> 3, col8 = (c & 7) * 8;
        uint4 v = *(const uint4*)(Wg + (size_t)row * Kp + kk + col8);
        *(uint4*)(&Bs[row * STR + col8]) = v;
      }
      __syncthreads();

      #pragma unroll
      for (int ksub = 0; ksub < 2; ksub++) {
        const int kbase = ksub * 32 + (lane >> 4) * 8;
        bf16x8 af[4], bfr[2];
        #pragma unroll
        for (int mi = 0; mi < 4; mi++)
          af[mi] = *(const bf16x8*)(&As[(mi * 16 + (lane & 15)) * STR + kbase]);
        #pragma unroll
        for (int ni = 0; ni < 2; ni++)
          bfr[ni] = *(const bf16x8*)(&Bs[(w * 32 + ni * 16 + (lane & 15)) * STR + kbase]);
        #pragma unroll
        for (int mi = 0; mi < 4; mi++)
          #pragma unroll
          for (int ni = 0; ni < 2; ni++)
            acc[mi][ni] = __builtin_amdgcn_mfma_f32_16x16x32_bf16(af[mi], bfr[ni], acc[mi][ni], 0, 0, 0);
      }
      __syncthreads();
    }

    // fold tile into running max (mask invalid t rows)
    const int rb = (lane >> 4) * 4;
    #pragma unroll
    for (int mi = 0; mi < 4; mi++) {
      int tbase = t0 + mi * 16 + rb;
      #pragma unroll
      for (int r = 0; r < 4; r++) {
        if (tbase + r < Lt) {
          rmax[0] = fmaxf(rmax[0], acc[mi][0][r]);
          rmax[1] = fmaxf(rmax[1], acc[mi][1][r]);
        }
      }
    }
  }

  // cross-lane max over the 4 lanes sharing each output column, then bias+relu+store
  const float* bias = (g == 0) ? b2v : (g == 1) ? b3v : b4v;
  #pragma unroll
  for (int ni = 0; ni < 2; ni++) {
    float v = rmax[ni];
    v = fmaxf(v, __shfl_xor(v, 16));
    v = fmaxf(v, __shfl_xor(v, 32));
    if (lane < 16) {
      int ch = chblk * BN + w * 32 + ni * 16 + lane;
      if (ch < NCH) {
        int n = ch / ODIM, o = ch - n * ODIM;
        out[b * (ODIM * 180) + o * 180 + g * 60 + n] = fmaxf(v + bias[ch], 0.f);
      }
    }
  }
}

extern "C" void kernel_launch(void* const* d_in, const int* in_sizes, int n_in,
                              void* d_out, int out_size, void* d_ws, size_t ws_size,
                              hipStream_t stream) {
  const float* x  = (const float*)d_in[0];
  const float* W2 = (const float*)d_in[1];
  const float* b2 = (const float*)d_in[2];
  const float* W3 = (const float*)d_in[3];
  const float* b3 = (const float*)d_in[4];
  const float* W4 = (const float*)d_in[5];
  const float* b4 = (const float*)d_in[6];
  float* out = (float*)d_out;

  u16* xb = (u16*)d_ws;            // XEL bf16
  u16* wb = xb + XEL;              // NCHP*(640+960+1216) bf16  (total ws use ~41.7 MB)

  cvt_x_kernel<<<XEL / (256 * 8), 256, 0, stream>>>(x, xb);
  repack_w_kernel<<<dim3(NCHP, 3), 256, 0, stream>>>(W2, W3, W4, wb);
  gemm_max_kernel<<<dim3(NCHP / BN, NB, 3), 256, 0, stream>>>(xb, wb, b2, b3, b4, out);
}

// Round 3
// 729.953 us; speedup vs baseline: 2.0079x; 2.0079x over previous
//
#include <hip/hip_runtime.h>
#include <cstdint>
#include <cstddef>

typedef unsigned short u16;
typedef unsigned int   u32;
typedef __attribute__((ext_vector_type(8))) short bf16x8;
typedef __attribute__((ext_vector_type(4))) float f32x4;

#define NB   16
#define LL   1024
#define CIN  300
#define CINP 320              /* padded channels: rows 640B -> 16B aligned */
#define XPBP (LL*CINP)        /* 327680 elements per batch (padded) */
#define XELP (NB*XPBP)        /* 5242880 */
#define NCH  6000
#define NCHP 6016             /* padded to 47*128 */
#define ODIM 100

#define BM 128
#define BN 128
#define BK 64

__device__ __forceinline__ u16 f2bf(float f) {
  union { float f; u32 u; } v; v.f = f;
  return (u16)((v.u + 0x7FFFu + ((v.u >> 16) & 1u)) >> 16);   // RNE, inputs finite
}

typedef __attribute__((address_space(1))) const unsigned int gu32;
typedef __attribute__((address_space(3))) unsigned int lu32;
__device__ __forceinline__ void gload_lds16(const void* g, void* l) {
  __builtin_amdgcn_global_load_lds((gu32*)g, (lu32*)l, 16, 0, 0);
}

// ---- x [16,1024,300] f32 -> xb [16,1024,320] bf16 (zero-pad channels) ----
__global__ void cvt_x_kernel(const float* __restrict__ x, u16* __restrict__ xb) {
  int i8 = (blockIdx.x * 256 + threadIdx.x) * 8;   // grid = XELP/(256*8) = 2560
  int row = i8 / CINP;                             // b*1024 + l
  int col = i8 - row * CINP;
  const float* src = x + (size_t)row * CIN + col;
  u16 e[8];
  if (col + 8 <= CIN) {
    float4 a = *(const float4*)src;
    float4 b = *(const float4*)(src + 4);
    e[0]=f2bf(a.x); e[1]=f2bf(a.y); e[2]=f2bf(a.z); e[3]=f2bf(a.w);
    e[4]=f2bf(b.x); e[5]=f2bf(b.y); e[6]=f2bf(b.z); e[7]=f2bf(b.w);
  } else {
    #pragma unroll
    for (int j = 0; j < 8; j++)
      e[j] = (col + j < CIN) ? f2bf(src[j]) : (u16)0;
  }
  uint4 o;
  o.x = (u32)e[0] | ((u32)e[1] << 16);
  o.y = (u32)e[2] | ((u32)e[3] << 16);
  o.z = (u32)e[4] | ((u32)e[5] << 16);
  o.w = (u32)e[6] | ((u32)e[7] << 16);
  *(uint4*)(xb + i8) = o;
}

// ---- W[n,o,c,j] f32 -> Wb[no][kp = j*320 + c] bf16 (zeros at c>=300, no>=6000)
__global__ void repack_w_kernel(const float* __restrict__ W2, const float* __restrict__ W3,
                                const float* __restrict__ W4, u16* __restrict__ wb) {
  int g = blockIdx.y;
  int kk = g + 2;
  int Kp = kk * CINP;
  int woff = (g == 0) ? 0 : (g == 1) ? NCHP*640 : NCHP*(640+960);
  const float* W = (g == 0) ? W2 : (g == 1) ? W3 : W4;
  int no = blockIdx.x;                       // 0..6015
  u16* dst = wb + (size_t)woff + (size_t)no * Kp;
  const float* src = W + (size_t)no * (CIN * kk);   // row no: [c][j]
  for (int kp = threadIdx.x; kp < Kp; kp += 256) {
    int j = kp / CINP, c = kp - j * CINP;
    u16 v = 0;
    if (no < NCH && c < CIN) v = f2bf(src[c * kk + j]);
    dst[kp] = v;
  }
}

// ---- fused GEMM + running-max + bias + relu (m97 structure) --------------
__global__ __launch_bounds__(256, 2)
void gemm_max_kernel(const u16* __restrict__ xb, const u16* __restrict__ wb,
                     const float* __restrict__ b2v, const float* __restrict__ b3v,
                     const float* __restrict__ b4v, float* __restrict__ out) {
  const int chblk = blockIdx.x;    // 0..46
  const int b     = blockIdx.y;    // 0..15
  const int g     = blockIdx.z;    // kernel size g+2
  const int Kp    = (g + 2) * CINP;                 // 640 / 960 / 1280
  const int woff  = (g == 0) ? 0 : (g == 1) ? NCHP*640 : NCHP*(640+960);
  const int Lt    = LL - (g + 2) + 1;

  __shared__ __align__(16) u16 As[BM * BK];   // 16 KB, linear (global_load_lds dest)
  __shared__ __align__(16) u16 Bs[BN * BK];   // 16 KB

  const int tid  = threadIdx.x;
  const int lane = tid & 63;
  const int w    = tid >> 6;       // wave 0..3
  const int wr   = w >> 1;         // wave row (0..1): owns 64 t-rows
  const int wc   = w & 1;          // wave col (0..1): owns 64 channels

  const u16* __restrict__ xrow = xb + (size_t)b * XPBP;
  const u16* __restrict__ Wg   = wb + (size_t)woff + (size_t)chblk * BN * Kp;

  const int lrow8 = lane >> 3;          // 0..7: row within 8-row segment
  const int lcol  = (lane & 7) * 8;     // element column of this lane's 16B

  float rmax[4] = { -1e30f, -1e30f, -1e30f, -1e30f };
  const int nks = Kp / BK;              // 10 / 15 / 20

  for (int t0 = 0; t0 < LL; t0 += BM) {
    f32x4 acc[4][4];
    #pragma unroll
    for (int mi = 0; mi < 4; mi++)
      #pragma unroll
      for (int ni = 0; ni < 4; ni++)
        acc[mi][ni] = (f32x4){0.f, 0.f, 0.f, 0.f};

    for (int ks = 0; ks < nks; ks++) {
      const int kk = ks * BK;
      // stage A [128 t][64 kp]: wave w owns rows w*32..w*32+31, 4 issues of 1KB
      #pragma unroll
      for (int i = 0; i < 4; i++) {
        int row = w * 32 + i * 8 + lrow8;
        gload_lds16(xrow + (size_t)(t0 + row) * CINP + kk + lcol,
                    &As[(w * 32 + i * 8) * BK]);
      }
      // stage B [128 ch][64 kp]
      #pragma unroll
      for (int i = 0; i < 4; i++) {
        int row = w * 32 + i * 8 + lrow8;
        gload_lds16(Wg + (size_t)row * Kp + kk + lcol,
                    &Bs[(w * 32 + i * 8) * BK]);
      }
      __syncthreads();   // compiler emits vmcnt(0) drain before barrier

      #pragma unroll
      for (int ksub = 0; ksub < 2; ksub++) {
        const int kb = ksub * 32 + (lane >> 4) * 8;
        bf16x8 af[4], bfr[4];
        #pragma unroll
        for (int mi = 0; mi < 4; mi++)
          af[mi] = *(const bf16x8*)(&As[(wr * 64 + mi * 16 + (lane & 15)) * BK + kb]);
        #pragma unroll
        for (int ni = 0; ni < 4; ni++)
          bfr[ni] = *(const bf16x8*)(&Bs[(wc * 64 + ni * 16 + (lane & 15)) * BK + kb]);
        #pragma unroll
        for (int mi = 0; mi < 4; mi++)
          #pragma unroll
          for (int ni = 0; ni < 4; ni++)
            acc[mi][ni] = __builtin_amdgcn_mfma_f32_16x16x32_bf16(af[mi], bfr[ni], acc[mi][ni], 0, 0, 0);
      }
      __syncthreads();
    }

    // fold tile into running max (mask t >= Lt rows)
    const int rb = (lane >> 4) * 4;
    #pragma unroll
    for (int mi = 0; mi < 4; mi++) {
      int tbase = t0 + wr * 64 + mi * 16 + rb;
      #pragma unroll
      for (int r = 0; r < 4; r++) {
        if (tbase + r < Lt) {
          #pragma unroll
          for (int ni = 0; ni < 4; ni++)
            rmax[ni] = fmaxf(rmax[ni], acc[mi][ni][r]);
        }
      }
    }
  }

  // --- epilogue ---
  // 1) intra-wave: max over the 4 row-groups sharing each column
  float cv[4];
  #pragma unroll
  for (int ni = 0; ni < 4; ni++) {
    float v = rmax[ni];
    v = fmaxf(v, __shfl_xor(v, 16));
    v = fmaxf(v, __shfl_xor(v, 32));
    cv[ni] = v;
  }
  // 2) cross-wave (wr=0 vs wr=1 cover different t halves!) reduction via LDS.
  //    Safe to reuse As: the k-loop's final __syncthreads drained all ds_reads.
  float* red = (float*)As;   // 256 floats: [wr][wc*64 + ni*16 + col]
  if (lane < 16) {
    #pragma unroll
    for (int ni = 0; ni < 4; ni++)
      red[wr * 128 + wc * 64 + ni * 16 + lane] = cv[ni];
  }
  __syncthreads();
  // 3) combine halves, bias + relu + scatter store
  const float* bias = (g == 0) ? b2v : (g == 1) ? b3v : b4v;
  if (tid < 128) {
    float v = fmaxf(red[tid], red[128 + tid]);
    int ch = chblk * BN + tid;
    if (ch < NCH) {
      int n = ch / ODIM, o = ch - n * ODIM;
      out[b * (ODIM * 180) + o * 180 + g * 60 + n] = fmaxf(v + bias[ch], 0.f);
    }
  }
}

extern "C" void kernel_launch(void* const* d_in, const int* in_sizes, int n_in,
                              void* d_out, int out_size, void* d_ws, size_t ws_size,
                              hipStream_t stream) {
  const float* x  = (const float*)d_in[0];
  const float* W2 = (const float*)d_in[1];
  const float* b2 = (const float*)d_in[2];
  const float* W3 = (const float*)d_in[3];
  const float* b3 = (const float*)d_in[4];
  const float* W4 = (const float*)d_in[5];
  const float* b4 = (const float*)d_in[6];
  float* out = (float*)d_out;

  u16* xb = (u16*)d_ws;            // XELP bf16 (10.5 MB)
  u16* wb = xb + XELP;             // NCHP*(640+960+1280) bf16 (34.7 MB)

  cvt_x_kernel<<<XELP / (256 * 8), 256, 0, stream>>>(x, xb);
  repack_w_kernel<<<dim3(NCHP, 3), 256, 0, stream>>>(W2, W3, W4, wb);
  gemm_max_kernel<<<dim3(NCHP / BN, NB, 3), 256, 0, stream>>>(xb, wb, b2, b3, b4, out);
}

// Round 4
// 557.763 us; speedup vs baseline: 2.6278x; 1.3087x over previous
//
#include <hip/hip_runtime.h>
#include <cstdint>
#include <cstddef>

typedef unsigned short u16;
typedef unsigned int   u32;
typedef __attribute__((ext_vector_type(8))) short bf16x8;
typedef __attribute__((ext_vector_type(4))) float f32x4;

#define NB   16
#define LL   1024
#define CIN  300
#define CINP 320              /* padded channels: rows 640B, 16B aligned */
#define XPBP (LL*CINP)        /* 327680 elems per batch */
#define XELP (NB*XPBP)        /* 5242880 */
#define NCH  6000
#define NCHP 6144             /* padded to 24*256 */
#define ODIM 100

#define BM 256
#define BN 256
#define BK 64

__device__ __forceinline__ u16 f2bf(float f) {
  union { float f; u32 u; } v; v.f = f;
  return (u16)((v.u + 0x7FFFu + ((v.u >> 16) & 1u)) >> 16);   // RNE, inputs finite
}

typedef __attribute__((address_space(1))) const unsigned int gu32;
typedef __attribute__((address_space(3))) unsigned int lu32;
__device__ __forceinline__ void gload_lds16(const void* g, void* l) {
  __builtin_amdgcn_global_load_lds((gu32*)g, (lu32*)l, 16, 0, 0);
}

#define BAR() asm volatile("s_barrier" ::: "memory")

// ---- x [16,1024,300] f32 -> xb [16,1024,320] bf16 (zero-pad channels) ----
__global__ void cvt_x_kernel(const float* __restrict__ x, u16* __restrict__ xb) {
  int i8 = (blockIdx.x * 256 + threadIdx.x) * 8;   // grid = XELP/(256*8) = 2560
  int row = i8 / CINP;
  int col = i8 - row * CINP;
  const float* src = x + (size_t)row * CIN + col;
  u16 e[8];
  if (col + 8 <= CIN) {
    float4 a = *(const float4*)src;
    float4 b = *(const float4*)(src + 4);
    e[0]=f2bf(a.x); e[1]=f2bf(a.y); e[2]=f2bf(a.z); e[3]=f2bf(a.w);
    e[4]=f2bf(b.x); e[5]=f2bf(b.y); e[6]=f2bf(b.z); e[7]=f2bf(b.w);
  } else {
    #pragma unroll
    for (int j = 0; j < 8; j++)
      e[j] = (col + j < CIN) ? f2bf(src[j]) : (u16)0;
  }
  uint4 o;
  o.x = (u32)e[0] | ((u32)e[1] << 16);
  o.y = (u32)e[2] | ((u32)e[3] << 16);
  o.z = (u32)e[4] | ((u32)e[5] << 16);
  o.w = (u32)e[6] | ((u32)e[7] << 16);
  *(uint4*)(xb + i8) = o;
}

// ---- W[n,o,c,j] f32 -> Wb[no][kp = j*320 + c] bf16 (zeros c>=300, no>=6000)
__global__ void repack_w_kernel(const float* __restrict__ W2, const float* __restrict__ W3,
                                const float* __restrict__ W4, u16* __restrict__ wb) {
  int g = blockIdx.y;
  int kk = g + 2;
  int Kp = kk * CINP;
  int woff = (g == 0) ? 0 : (g == 1) ? NCHP*640 : NCHP*(640+960);
  const float* W = (g == 0) ? W2 : (g == 1) ? W3 : W4;
  int no = blockIdx.x;                       // 0..6143
  u16* dst = wb + (size_t)woff + (size_t)no * Kp;
  const float* src = W + (size_t)no * (CIN * kk);
  for (int kp = threadIdx.x; kp < Kp; kp += 256) {
    int j = kp / CINP, c = kp - j * CINP;
    u16 v = 0;
    if (no < NCH && c < CIN) v = f2bf(src[c * kk + j]);
    dst[kp] = v;
  }
}

// ---- fused GEMM + running-max + bias + relu (256^2 8-phase, T2+T3+T4+T5) --
// Phase p of tile t:
//   ds_read frags (swizzled) | issue 1 half-tile stage for t+1 | BAR |
//   [compiler lgkmcnt] setprio(1) 16xMFMA setprio(0) | counted vmcnt | BAR
// Issue order per tile: [A0,B0,B1,A1]; quadrants (mh,nh)=(00),(01),(10),(11).
// Steady vmcnt(4) at ph1/ph2/ph4 (derived by queue tracking); last tile 2->0.
__global__ __launch_bounds__(512, 1)
void gemm_max_kernel(const u16* __restrict__ xb, const u16* __restrict__ wb,
                     const float* __restrict__ b2v, const float* __restrict__ b3v,
                     const float* __restrict__ b4v, float* __restrict__ out) {
  const int chblk = blockIdx.x;    // 0..23
  const int b     = blockIdx.y;    // 0..15
  const int g     = blockIdx.z;    // kernel size g+2
  const int Kp    = (g + 2) * CINP;                 // 640 / 960 / 1280
  const int nks   = Kp >> 6;                        // 10 / 15 / 20
  const int woff  = (g == 0) ? 0 : (g == 1) ? NCHP*640 : NCHP*(640+960);
  const int Lt    = LL - (g + 2) + 1;

  __shared__ __align__(16) u16 smem[4 * 16384];     // 128 KiB
  u16* A0s = smem;
  u16* B0s = smem + 16384;
  u16* A1s = smem + 32768;
  u16* B1s = smem + 49152;

  const int tid  = threadIdx.x;
  const int lane = tid & 63;
  const int w    = tid >> 6;       // 0..7
  const int wr   = w >> 2;         // 0..1 : M interleave
  const int wc   = w & 3;          // 0..3 : N interleave

  const u16* __restrict__ xrow = xb + (size_t)b * XPBP;
  const u16* __restrict__ Wg   = wb + (size_t)woff + (size_t)chblk * BN * Kp;

  // stage one 128x64 half: linear LDS dest (wave-uniform base), inverse-swizzled src
  auto STAGE = [&](const u16* src, int stride, u16* buf, int half) {
    #pragma unroll
    for (int i = 0; i < 2; i++) {
      int c = i * 512 + w * 64 + lane;                  // chunk 0..1023
      int row128 = c >> 3;
      int colb = ((c & 7) * 16) ^ ((row128 & 7) << 4);  // inverse swizzle (involution)
      gload_lds16(src + (size_t)(half * 128 + row128) * stride + (colb >> 1),
                  buf + half * 8192 + i * 4096 + w * 512);
    }
  };

  // swizzled fragment read: group grp (16 rows), ksub k
  auto FR = [&](const u16* buf, int grp, int k) -> bf16x8 {
    int row  = grp * 16 + (lane & 15);
    int colb = (k * 64 + ((lane >> 4) << 4)) ^ ((lane & 7) << 4);  // row&7 == lane&7
    return *(const bf16x8*)(buf + row * 64 + (colb >> 1));
  };

  f32x4 acc[8][4];
  #pragma unroll
  for (int mi = 0; mi < 8; mi++)
    #pragma unroll
    for (int ni = 0; ni < 4; ni++)
      acc[mi][ni] = (f32x4){0.f, 0.f, 0.f, 0.f};

  bf16x8 afr[4][2];       // current A-half frags
  bf16x8 bfr[2][2][2];    // [nh][b2][k2], both B halves held
  float rmax[4] = { -1e30f, -1e30f, -1e30f, -1e30f };

  auto FOLD = [&](int ttf) {
    #pragma unroll
    for (int mi = 0; mi < 8; mi++) {
      int tb = ttf * 256 + (mi * 2 + wr) * 16 + ((lane >> 4) << 2);
      #pragma unroll
      for (int r = 0; r < 4; r++) {
        bool ok = (tb + r) < Lt;
        #pragma unroll
        for (int ni = 0; ni < 4; ni++)
          if (ok) rmax[ni] = fmaxf(rmax[ni], acc[mi][ni][r]);
      }
      #pragma unroll
      for (int ni = 0; ni < 4; ni++)
        acc[mi][ni] = (f32x4){0.f, 0.f, 0.f, 0.f};
    }
  };

#define PHASE(CA, CB, MHC, NH, RA, RB, STG, VM) do {                          \
    if (RA) {                                                                 \
      _Pragma("unroll")                                                       \
      for (int a2 = 0; a2 < 4; a2++) {                                        \
        _Pragma("unroll")                                                     \
        for (int k2 = 0; k2 < 2; k2++)                                        \
          afr[a2][k2] = FR(CA, ((MHC)*4 + a2) * 2 + wr, k2);                  \
      }                                                                       \
    }                                                                         \
    if (RB) {                                                                 \
      _Pragma("unroll")                                                       \
      for (int b2 = 0; b2 < 2; b2++) {                                        \
        _Pragma("unroll")                                                     \
        for (int k2 = 0; k2 < 2; k2++)                                        \
          bfr[NH][b2][k2] = FR(CB, ((NH)*2 + b2) * 4 + wc, k2);               \
      }                                                                       \
    }                                                                         \
    STG;                                                                      \
    BAR();                                                                    \
    __builtin_amdgcn_s_setprio(1);                                            \
    _Pragma("unroll")                                                         \
    for (int a2 = 0; a2 < 4; a2++)                                            \
      _Pragma("unroll")                                                       \
      for (int b2 = 0; b2 < 2; b2++)                                          \
        _Pragma("unroll")                                                     \
        for (int k2 = 0; k2 < 2; k2++)                                        \
          acc[(MHC)*4 + a2][(NH)*2 + b2] =                                    \
            __builtin_amdgcn_mfma_f32_16x16x32_bf16(afr[a2][k2],              \
              bfr[NH][b2][k2], acc[(MHC)*4 + a2][(NH)*2 + b2], 0, 0, 0);      \
    __builtin_amdgcn_s_setprio(0);                                            \
    VM;                                                                       \
    BAR();                                                                    \
  } while (0)

  const int NT = 4 * nks;    // 40 / 60 / 80 (always even)
  int tt = 0, ks = 0;

  // ---- prologue: tile0 -> buf0, order [A0,B0,B1,A1] ----
  STAGE(xrow, CINP, A0s, 0);
  STAGE(Wg,   Kp,   B0s, 0);
  STAGE(Wg,   Kp,   B0s, 1);
  STAGE(xrow, CINP, A0s, 1);
  asm volatile("s_waitcnt vmcnt(4)" ::: "memory");
  BAR();

  // ---- steady K-loop (tiles 0 .. NT-2) ----
  for (int s = 0; s < NT - 1; s++) {
    int ks2 = ks + 1, tt2 = tt;
    if (ks2 == nks) { ks2 = 0; tt2++; }
    const u16* sA = xrow + (size_t)tt2 * (256 * CINP) + ks2 * 64;
    const u16* sB = Wg + ks2 * 64;
    u16* cA = (s & 1) ? A1s : A0s;
    u16* cB = (s & 1) ? B1s : B0s;
    u16* nA = (s & 1) ? A0s : A1s;
    u16* nB = (s & 1) ? B0s : B1s;

    PHASE(cA, cB, 0, 0, 1, 1, STAGE(sA, CINP, nA, 0),
          asm volatile("s_waitcnt vmcnt(4)" ::: "memory"));
    PHASE(cA, cB, 0, 1, 0, 1, STAGE(sB, Kp,   nB, 0),
          asm volatile("s_waitcnt vmcnt(4)" ::: "memory"));
    PHASE(cA, cB, 1, 0, 1, 0, STAGE(sB, Kp,   nB, 1),
          ((void)0));
    PHASE(cA, cB, 1, 1, 0, 0, STAGE(sA, CINP, nA, 1),
          asm volatile("s_waitcnt vmcnt(4) lgkmcnt(0)" ::: "memory"));

    if (++ks == nks) { FOLD(tt); ks = 0; tt++; }
  }

  // ---- peeled last tile (reads buf1; no staging; drain 2 -> 0) ----
  {
    u16* cA = A1s;   // NT even -> last tile parity 1
    u16* cB = B1s;
    PHASE(cA, cB, 0, 0, 1, 1, ((void)0),
          asm volatile("s_waitcnt vmcnt(2)" ::: "memory"));
    PHASE(cA, cB, 0, 1, 0, 1, ((void)0),
          asm volatile("s_waitcnt vmcnt(0)" ::: "memory"));
    PHASE(cA, cB, 1, 0, 1, 0, ((void)0), ((void)0));
    PHASE(cA, cB, 1, 1, 0, 0, ((void)0),
          asm volatile("s_waitcnt lgkmcnt(0)" ::: "memory"));
    FOLD(tt);
  }
#undef PHASE

  // ---- epilogue: intra-wave max, cross-wave (wr pair) combine, bias+relu ----
  float cv[4];
  #pragma unroll
  for (int ni = 0; ni < 4; ni++) {
    float v = rmax[ni];
    v = fmaxf(v, __shfl_xor(v, 16));
    v = fmaxf(v, __shfl_xor(v, 32));
    cv[ni] = v;
  }
  __syncthreads();                    // full drain; smem reusable
  float* red = (float*)smem;          // 512 floats: [wr][gn*16 + col]
  if (lane < 16) {
    #pragma unroll
    for (int ni = 0; ni < 4; ni++)
      red[wr * 256 + (ni * 4 + wc) * 16 + lane] = cv[ni];
  }
  __syncthreads();
  const float* bias = (g == 0) ? b2v : (g == 1) ? b3v : b4v;
  if (tid < 256) {
    float v = fmaxf(red[tid], red[256 + tid]);
    int ch = chblk * BN + tid;
    if (ch < NCH) {
      int n = ch / ODIM, o = ch - n * ODIM;
      out[b * (ODIM * 180) + o * 180 + g * 60 + n] = fmaxf(v + bias[ch], 0.f);
    }
  }
}

extern "C" void kernel_launch(void* const* d_in, const int* in_sizes, int n_in,
                              void* d_out, int out_size, void* d_ws, size_t ws_size,
                              hipStream_t stream) {
  const float* x  = (const float*)d_in[0];
  const float* W2 = (const float*)d_in[1];
  const float* b2 = (const float*)d_in[2];
  const float* W3 = (const float*)d_in[3];
  const float* b3 = (const float*)d_in[4];
  const float* W4 = (const float*)d_in[5];
  const float* b4 = (const float*)d_in[6];
  float* out = (float*)d_out;

  u16* xb = (u16*)d_ws;            // XELP bf16 (10.5 MB)
  u16* wb = xb + XELP;             // NCHP*(640+960+1280) bf16 (35.4 MB)

  cvt_x_kernel<<<XELP / (256 * 8), 256, 0, stream>>>(x, xb);
  repack_w_kernel<<<dim3(NCHP, 3), 256, 0, stream>>>(W2, W3, W4, wb);
  gemm_max_kernel<<<dim3(NCHP / BN, NB, 3), 512, 0, stream>>>(xb, wb, b2, b3, b4, out);
}

// Round 5
// 531.942 us; speedup vs baseline: 2.7553x; 1.0485x over previous
//
#include <hip/hip_runtime.h>
#include <cstdint>
#include <cstddef>

typedef unsigned short u16;
typedef unsigned int   u32;
typedef __attribute__((ext_vector_type(8))) short bf16x8;
typedef __attribute__((ext_vector_type(4))) float f32x4;

#define NB   16
#define LL   1024
#define CIN  300
#define CINP 320              /* padded channels: rows 640B, 16B aligned */
#define XPBP (LL*CINP)        /* 327680 elems per batch */
#define XELP (NB*XPBP)        /* 5242880 */
#define NCH  6000
#define NCHP 6144             /* padded to 24*256 */
#define ODIM 100

#define BM 256
#define BN 256
#define BK 64

__device__ __forceinline__ u16 f2bf(float f) {
  union { float f; u32 u; } v; v.f = f;
  return (u16)((v.u + 0x7FFFu + ((v.u >> 16) & 1u)) >> 16);   // RNE, inputs finite
}

typedef __attribute__((address_space(1))) const unsigned int gu32;
typedef __attribute__((address_space(3))) unsigned int lu32;
__device__ __forceinline__ void gload_lds16(const void* g, void* l) {
  __builtin_amdgcn_global_load_lds((gu32*)g, (lu32*)l, 16, 0, 0);
}

#define BAR() asm volatile("s_barrier" ::: "memory")

// ---- x [16,1024,300] f32 -> xb [16,1024,320] bf16 (zero-pad channels) ----
__global__ void cvt_x_kernel(const float* __restrict__ x, u16* __restrict__ xb) {
  int i8 = (blockIdx.x * 256 + threadIdx.x) * 8;   // grid = XELP/(256*8) = 2560
  int row = i8 / CINP;
  int col = i8 - row * CINP;
  const float* src = x + (size_t)row * CIN + col;
  u16 e[8];
  if (col + 8 <= CIN) {
    float4 a = *(const float4*)src;
    float4 b = *(const float4*)(src + 4);
    e[0]=f2bf(a.x); e[1]=f2bf(a.y); e[2]=f2bf(a.z); e[3]=f2bf(a.w);
    e[4]=f2bf(b.x); e[5]=f2bf(b.y); e[6]=f2bf(b.z); e[7]=f2bf(b.w);
  } else {
    #pragma unroll
    for (int j = 0; j < 8; j++)
      e[j] = (col + j < CIN) ? f2bf(src[j]) : (u16)0;
  }
  uint4 o;
  o.x = (u32)e[0] | ((u32)e[1] << 16);
  o.y = (u32)e[2] | ((u32)e[3] << 16);
  o.z = (u32)e[4] | ((u32)e[5] << 16);
  o.w = (u32)e[6] | ((u32)e[7] << 16);
  *(uint4*)(xb + i8) = o;
}

// ---- W[n,o,c,j] f32 -> Wb[no][kp = j*320 + c] bf16 (zeros c>=300, no>=6000)
__global__ void repack_w_kernel(const float* __restrict__ W2, const float* __restrict__ W3,
                                const float* __restrict__ W4, u16* __restrict__ wb) {
  int g = blockIdx.y;
  int kk = g + 2;
  int Kp = kk * CINP;
  int woff = (g == 0) ? 0 : (g == 1) ? NCHP*640 : NCHP*(640+960);
  const float* W = (g == 0) ? W2 : (g == 1) ? W3 : W4;
  int no = blockIdx.x;                       // 0..6143
  u16* dst = wb + (size_t)woff + (size_t)no * Kp;
  const float* src = W + (size_t)no * (CIN * kk);
  for (int kp = threadIdx.x; kp < Kp; kp += 256) {
    int j = kp / CINP, c = kp - j * CINP;
    u16 v = 0;
    if (no < NCH && c < CIN) v = f2bf(src[c * kk + j]);
    dst[kp] = v;
  }
}

// ---- fused GEMM + running-max + bias + relu (256^2 8-phase, T2+T3+T4+T5) --
// LPT grid: flat 1-D, heavy g=2 blocks dispatch first (tail balance).
// Phase p of tile t:
//   ds_read frags (swizzled) | issue 1 half-tile stage for t+1 | BAR |
//   [compiler lgkmcnt] setprio(1) 16xMFMA setprio(0) | counted vmcnt | BAR
// Issue order per tile: [A0,B0,B1,A1]; quadrants (mh,nh)=(00),(01),(10),(11).
// Steady vmcnt(4) at ph1/ph2/ph4 (derived by queue tracking); last tile 2->0.
__global__ __launch_bounds__(512, 1)
void gemm_max_kernel(const u16* __restrict__ xb, const u16* __restrict__ wb,
                     const float* __restrict__ b2v, const float* __restrict__ b3v,
                     const float* __restrict__ b4v, float* __restrict__ out) {
  // LPT remap: ids 0..383 -> g=2, 384..767 -> g=1, 768..1151 -> g=0
  const int id    = blockIdx.x;
  const int g     = 2 - (id / 384);
  const int id2   = id % 384;
  const int b     = id2 / 24;      // 0..15
  const int chblk = id2 % 24;      // 0..23
  const int Kp    = (g + 2) * CINP;                 // 640 / 960 / 1280
  const int nks   = Kp >> 6;                        // 10 / 15 / 20
  const int woff  = (g == 0) ? 0 : (g == 1) ? NCHP*640 : NCHP*(640+960);
  const int Lt    = LL - (g + 2) + 1;

  __shared__ __align__(16) u16 smem[4 * 16384];     // 128 KiB
  u16* A0s = smem;
  u16* B0s = smem + 16384;
  u16* A1s = smem + 32768;
  u16* B1s = smem + 49152;

  const int tid  = threadIdx.x;
  const int lane = tid & 63;
  const int w    = tid >> 6;       // 0..7
  const int wr   = w >> 2;         // 0..1 : M interleave
  const int wc   = w & 3;          // 0..3 : N interleave

  const u16* __restrict__ xrow = xb + (size_t)b * XPBP;
  const u16* __restrict__ Wg   = wb + (size_t)woff + (size_t)chblk * BN * Kp;

  // stage one 128x64 half: linear LDS dest (wave-uniform base), inverse-swizzled src
  auto STAGE = [&](const u16* src, int stride, u16* buf, int half) {
    #pragma unroll
    for (int i = 0; i < 2; i++) {
      int c = i * 512 + w * 64 + lane;                  // chunk 0..1023
      int row128 = c >> 3;
      int colb = ((c & 7) * 16) ^ ((row128 & 7) << 4);  // inverse swizzle (involution)
      gload_lds16(src + (size_t)(half * 128 + row128) * stride + (colb >> 1),
                  buf + half * 8192 + i * 4096 + w * 512);
    }
  };

  // swizzled fragment read: group grp (16 rows), ksub k
  auto FR = [&](const u16* buf, int grp, int k) -> bf16x8 {
    int row  = grp * 16 + (lane & 15);
    int colb = (k * 64 + ((lane >> 4) << 4)) ^ ((lane & 7) << 4);  // row&7 == lane&7
    return *(const bf16x8*)(buf + row * 64 + (colb >> 1));
  };

  f32x4 acc[8][4];
  #pragma unroll
  for (int mi = 0; mi < 8; mi++)
    #pragma unroll
    for (int ni = 0; ni < 4; ni++)
      acc[mi][ni] = (f32x4){0.f, 0.f, 0.f, 0.f};

  bf16x8 afr[4][2];       // current A-half frags
  bf16x8 bfr[2][2][2];    // [nh][b2][k2], both B halves held
  float rmax[4] = { -1e30f, -1e30f, -1e30f, -1e30f };

  auto FOLD = [&](int ttf) {
    #pragma unroll
    for (int mi = 0; mi < 8; mi++) {
      int tb = ttf * 256 + (mi * 2 + wr) * 16 + ((lane >> 4) << 2);
      #pragma unroll
      for (int r = 0; r < 4; r++) {
        bool ok = (tb + r) < Lt;
        #pragma unroll
        for (int ni = 0; ni < 4; ni++)
          if (ok) rmax[ni] = fmaxf(rmax[ni], acc[mi][ni][r]);
      }
      #pragma unroll
      for (int ni = 0; ni < 4; ni++)
        acc[mi][ni] = (f32x4){0.f, 0.f, 0.f, 0.f};
    }
  };

#define PHASE(CA, CB, MHC, NH, RA, RB, STG, VM) do {                          \
    if (RA) {                                                                 \
      _Pragma("unroll")                                                       \
      for (int a2 = 0; a2 < 4; a2++) {                                        \
        _Pragma("unroll")                                                     \
        for (int k2 = 0; k2 < 2; k2++)                                        \
          afr[a2][k2] = FR(CA, ((MHC)*4 + a2) * 2 + wr, k2);                  \
      }                                                                       \
    }                                                                         \
    if (RB) {                                                                 \
      _Pragma("unroll")                                                       \
      for (int b2 = 0; b2 < 2; b2++) {                                        \
        _Pragma("unroll")                                                     \
        for (int k2 = 0; k2 < 2; k2++)                                        \
          bfr[NH][b2][k2] = FR(CB, ((NH)*2 + b2) * 4 + wc, k2);               \
      }                                                                       \
    }                                                                         \
    STG;                                                                      \
    BAR();                                                                    \
    __builtin_amdgcn_s_setprio(1);                                            \
    _Pragma("unroll")                                                         \
    for (int a2 = 0; a2 < 4; a2++)                                            \
      _Pragma("unroll")                                                       \
      for (int b2 = 0; b2 < 2; b2++)                                          \
        _Pragma("unroll")                                                     \
        for (int k2 = 0; k2 < 2; k2++)                                        \
          acc[(MHC)*4 + a2][(NH)*2 + b2] =                                    \
            __builtin_amdgcn_mfma_f32_16x16x32_bf16(afr[a2][k2],              \
              bfr[NH][b2][k2], acc[(MHC)*4 + a2][(NH)*2 + b2], 0, 0, 0);      \
    __builtin_amdgcn_s_setprio(0);                                            \
    VM;                                                                       \
    BAR();                                                                    \
  } while (0)

  const int NT = 4 * nks;    // 40 / 60 / 80 (always even)
  int tt = 0, ks = 0;

  // ---- prologue: tile0 -> buf0, order [A0,B0,B1,A1] ----
  STAGE(xrow, CINP, A0s, 0);
  STAGE(Wg,   Kp,   B0s, 0);
  STAGE(Wg,   Kp,   B0s, 1);
  STAGE(xrow, CINP, A0s, 1);
  asm volatile("s_waitcnt vmcnt(4)" ::: "memory");
  BAR();

  // ---- steady K-loop (tiles 0 .. NT-2) ----
  for (int s = 0; s < NT - 1; s++) {
    int ks2 = ks + 1, tt2 = tt;
    if (ks2 == nks) { ks2 = 0; tt2++; }
    const u16* sA = xrow + (size_t)tt2 * (256 * CINP) + ks2 * 64;
    const u16* sB = Wg + ks2 * 64;
    u16* cA = (s & 1) ? A1s : A0s;
    u16* cB = (s & 1) ? B1s : B0s;
    u16* nA = (s & 1) ? A0s : A1s;
    u16* nB = (s & 1) ? B0s : B1s;

    PHASE(cA, cB, 0, 0, 1, 1, STAGE(sA, CINP, nA, 0),
          asm volatile("s_waitcnt vmcnt(4)" ::: "memory"));
    PHASE(cA, cB, 0, 1, 0, 1, STAGE(sB, Kp,   nB, 0),
          asm volatile("s_waitcnt vmcnt(4)" ::: "memory"));
    PHASE(cA, cB, 1, 0, 1, 0, STAGE(sB, Kp,   nB, 1),
          ((void)0));
    PHASE(cA, cB, 1, 1, 0, 0, STAGE(sA, CINP, nA, 1),
          asm volatile("s_waitcnt vmcnt(4) lgkmcnt(0)" ::: "memory"));

    if (++ks == nks) { FOLD(tt); ks = 0; tt++; }
  }

  // ---- peeled last tile (reads buf1; no staging; drain 2 -> 0) ----
  {
    u16* cA = A1s;   // NT even -> last tile parity 1
    u16* cB = B1s;
    PHASE(cA, cB, 0, 0, 1, 1, ((void)0),
          asm volatile("s_waitcnt vmcnt(2)" ::: "memory"));
    PHASE(cA, cB, 0, 1, 0, 1, ((void)0),
          asm volatile("s_waitcnt vmcnt(0)" ::: "memory"));
    PHASE(cA, cB, 1, 0, 1, 0, ((void)0), ((void)0));
    PHASE(cA, cB, 1, 1, 0, 0, ((void)0),
          asm volatile("s_waitcnt lgkmcnt(0)" ::: "memory"));
    FOLD(tt);
  }
#undef PHASE

  // ---- epilogue: intra-wave max, cross-wave (wr pair) combine, bias+relu ----
  float cv[4];
  #pragma unroll
  for (int ni = 0; ni < 4; ni++) {
    float v = rmax[ni];
    v = fmaxf(v, __shfl_xor(v, 16));
    v = fmaxf(v, __shfl_xor(v, 32));
    cv[ni] = v;
  }
  __syncthreads();                    // full drain; smem reusable
  float* red = (float*)smem;          // 512 floats: [wr][gn*16 + col]
  if (lane < 16) {
    #pragma unroll
    for (int ni = 0; ni < 4; ni++)
      red[wr * 256 + (ni * 4 + wc) * 16 + lane] = cv[ni];
  }
  __syncthreads();
  const float* bias = (g == 0) ? b2v : (g == 1) ? b3v : b4v;
  if (tid < 256) {
    float v = fmaxf(red[tid], red[256 + tid]);
    int ch = chblk * BN + tid;
    if (ch < NCH) {
      int n = ch / ODIM, o = ch - n * ODIM;
      out[b * (ODIM * 180) + o * 180 + g * 60 + n] = fmaxf(v + bias[ch], 0.f);
    }
  }
}

extern "C" void kernel_launch(void* const* d_in, const int* in_sizes, int n_in,
                              void* d_out, int out_size, void* d_ws, size_t ws_size,
                              hipStream_t stream) {
  const float* x  = (const float*)d_in[0];
  const float* W2 = (const float*)d_in[1];
  const float* b2 = (const float*)d_in[2];
  const float* W3 = (const float*)d_in[3];
  const float* b3 = (const float*)d_in[4];
  const float* W4 = (const float*)d_in[5];
  const float* b4 = (const float*)d_in[6];
  float* out = (float*)d_out;

  u16* xb = (u16*)d_ws;            // XELP bf16 (10.5 MB)
  u16* wb = xb + XELP;             // NCHP*(640+960+1280) bf16 (35.4 MB)

  cvt_x_kernel<<<XELP / (256 * 8), 256, 0, stream>>>(x, xb);
  repack_w_kernel<<<dim3(NCHP, 3), 256, 0, stream>>>(W2, W3, W4, wb);
  gemm_max_kernel<<<dim3(1152), 512, 0, stream>>>(xb, wb, b2, b3, b4, out);
}